// Round 1
// baseline (157.849 us; speedup 1.0000x reference)
//
#include <hip/hip_runtime.h>
#include <hip/hip_bf16.h>
#include <math.h>

// ---------------------------------------------------------------------------
// Fused MoE top-2 router, MI355X (gfx950).
// logits = x @ W^T (8192x4096 * 64x4096^T), softmax, top-2, z-loss,
// load-balance loss, logits mean.
//
// Layout: grid 256 blocks x 256 threads. Block handles 32 tokens.
// Wave (64 lanes) = 8 tokens x 8 k-slices. Lane accumulates all 64 experts
// for (token ts, k subset {c*256 + kk*32 + ks*4 + j}).
// W chunk (64 experts x 256 k, 64 KiB) double-buffered in LDS via
// global_load_lds; reads are 8-way broadcast, bank-conflict-free.
// Epilogue: shfl_xor butterfly over k-slices -> full logits in registers ->
// softmax/top-2/reductions fused; 3 scalars finalized by a tiny 2nd kernel.
// ---------------------------------------------------------------------------

#define NT 8192
#define ND 4096
#define NE 64
#define BK 256
#define NCHUNK (ND / BK)   // 16
#define KK (BK / 32)       // 8

__device__ __forceinline__ void gload16(const float* g, float* l) {
    __builtin_amdgcn_global_load_lds(
        (const __attribute__((address_space(1))) void*)g,
        (__attribute__((address_space(3))) void*)l, 16, 0, 0);
}

__global__ __launch_bounds__(256, 1)
void router_main(const float* __restrict__ x, const float* __restrict__ W,
                 float* __restrict__ out, float* __restrict__ ws)
{
    __shared__ float wlds[2][NE * BK];   // 2 x 64 KiB
    __shared__ float imp_s[NE];
    __shared__ float load_s[NE];
    __shared__ float z_s;
    __shared__ float lsum_s;

    const int tid = threadIdx.x;
    if (tid < NE) { imp_s[tid] = 0.f; load_s[tid] = 0.f; }
    if (tid == NE) z_s = 0.f;
    if (tid == NE + 1) lsum_s = 0.f;

    const int lane = tid & 63;
    const int wave = tid >> 6;
    const int ts   = lane >> 3;   // token within wave 0..7
    const int ks   = lane & 7;    // k-slice 0..7
    const int tok  = blockIdx.x * 32 + wave * 8 + ts;
    const float* xrow = x + (size_t)tok * ND;

    float acc[NE];
    #pragma unroll
    for (int e = 0; e < NE; e++) acc[e] = 0.f;

    // prologue: stage chunk 0 -> buffer 0
    #pragma unroll
    for (int r = 0; r < 16; r++) {
        const int f4 = r * 256 + tid;
        const int e  = f4 >> 6;
        const int kp = (f4 & 63) << 2;
        gload16(W + (size_t)e * ND + kp, &wlds[0][f4 * 4]);
    }
    __syncthreads();   // drains vmcnt(0): buffer 0 ready

    for (int c = 0; c < NCHUNK; c++) {
        const int b = c & 1;
        if (c + 1 < NCHUNK) {
            // prefetch next chunk into the other buffer (overlaps compute)
            #pragma unroll
            for (int r = 0; r < 16; r++) {
                const int f4 = r * 256 + tid;
                const int e  = f4 >> 6;
                const int kp = (f4 & 63) << 2;
                gload16(W + (size_t)e * ND + (c + 1) * BK + kp,
                        &wlds[b ^ 1][f4 * 4]);
            }
        }

        // x fragments for this chunk (coalesced: 8 ks-lanes cover a 128B line)
        float4 xv[KK];
        const float* xp = xrow + c * BK + ks * 4;
        #pragma unroll
        for (int kk = 0; kk < KK; kk++)
            xv[kk] = *reinterpret_cast<const float4*>(xp + kk * 32);

        const float* wb = wlds[b];
        #pragma unroll
        for (int kk = 0; kk < KK; kk++) {
            const float xs[4] = { xv[kk].x, xv[kk].y, xv[kk].z, xv[kk].w };
            #pragma unroll
            for (int eb = 0; eb < NE / 8; eb++) {
                float wv[8][4];
                #pragma unroll
                for (int e = 0; e < 8; e++) {
                    const float4 t = *reinterpret_cast<const float4*>(
                        wb + (eb * 8 + e) * BK + kk * 32 + ks * 4);
                    wv[e][0] = t.x; wv[e][1] = t.y; wv[e][2] = t.z; wv[e][3] = t.w;
                }
                #pragma unroll
                for (int j = 0; j < 4; j++) {
                    #pragma unroll
                    for (int e = 0; e < 8; e++)
                        acc[eb * 8 + e] = fmaf(xs[j], wv[e][j], acc[eb * 8 + e]);
                }
            }
        }
        __syncthreads();   // buffer reuse fence + drains prefetch
    }

    // ---- reduce k-slices: butterfly over lanes differing in ks bits ----
    #pragma unroll
    for (int e = 0; e < NE; e++) {
        acc[e] += __shfl_xor(acc[e], 1);
        acc[e] += __shfl_xor(acc[e], 2);
        acc[e] += __shfl_xor(acc[e], 4);
    }
    // every lane now holds the token's full 64 logits

    float m = -3.0e38f;
    #pragma unroll
    for (int e = 0; e < NE; e++) m = fmaxf(m, acc[e]);
    float se = 0.f;
    #pragma unroll
    for (int e = 0; e < NE; e++) se += __expf(acc[e] - m);
    const float lse = m + __logf(se);

    // top-2 (ties: lower index ranks first, matching lax.top_k)
    float v1 = -3.0e38f, v2 = -3.0e38f;
    int   i1 = 0, i2 = 0;
    #pragma unroll
    for (int e = 0; e < NE; e++) {
        const float v = acc[e];
        if (v > v1)      { v2 = v1; i2 = i1; v1 = v; i1 = e; }
        else if (v > v2) { v2 = v;  i2 = e; }
    }
    const float inv = 1.f / se;
    const float p1 = __expf(v1 - m) * inv;
    const float p2 = __expf(v2 - m) * inv;
    const float dn = fmaxf(p1 + p2, 1e-9f);

    float ssum = 0.f;
    #pragma unroll
    for (int e = 0; e < NE; e++) ssum += acc[e];

    if (ks == 0) {
        out[2 * tok]          = (float)i1;
        out[2 * tok + 1]      = (float)i2;
        out[2 * NT + 2 * tok]     = p1 / dn;
        out[2 * NT + 2 * tok + 1] = p2 / dn;
        atomicAdd(&z_s, lse * lse);
        atomicAdd(&load_s[i1], 1.0f);
    }
    if (ks == 1) atomicAdd(&lsum_s, ssum);

    // importance: p per expert, reduce over the wave's 8 tokens, then one
    // atomic per expert from the ts==0 lanes (compile-time e indexing only)
    #pragma unroll
    for (int e = 0; e < NE; e++) {
        float p = __expf(acc[e] - m) * inv;
        p += __shfl_xor(p, 8);
        p += __shfl_xor(p, 16);
        p += __shfl_xor(p, 32);
        if (ts == 0 && ks == (e >> 3)) atomicAdd(&imp_s[e], p);
    }

    __syncthreads();
    if (tid < NE) {
        atomicAdd(&ws[tid], imp_s[tid]);
        atomicAdd(&ws[NE + tid], load_s[tid]);
    }
    if (tid == NE)     atomicAdd(&ws[128], z_s);
    if (tid == NE + 1) atomicAdd(&ws[129], lsum_s);
}

__global__ void finalize(const float* __restrict__ ws, float* __restrict__ out)
{
    const int l = threadIdx.x;   // 64 threads, one wave
    const float imp = ws[l];
    const float ld  = ws[NE + l];
    float is = imp, ls = ld;
    for (int mk = 1; mk < 64; mk <<= 1) { is += __shfl_xor(is, mk); ls += __shfl_xor(ls, mk); }
    float v = (imp / fmaxf(is, 1e-9f)) * (ld / fmaxf(ls, 1e-9f));
    for (int mk = 1; mk < 64; mk <<= 1) v += __shfl_xor(v, mk);
    if (l == 0) {
        out[4 * NT]     = (ws[128] / (float)NT) * 0.001f;            // router_z_loss
        out[4 * NT + 1] = v * (float)(NE * NE) * 0.01f;              // load_balance_loss
        out[4 * NT + 2] = ws[129] / (float)((size_t)NT * NE);        // logits_mean
    }
}

extern "C" void kernel_launch(void* const* d_in, const int* in_sizes, int n_in,
                              void* d_out, int out_size, void* d_ws, size_t ws_size,
                              hipStream_t stream) {
    const float* x = (const float*)d_in[0];
    const float* W = (const float*)d_in[1];
    float* out = (float*)d_out;
    float* ws  = (float*)d_ws;

    hipMemsetAsync(ws, 0, 130 * sizeof(float), stream);
    hipLaunchKernelGGL(router_main, dim3(NT / 32), dim3(256), 0, stream, x, W, out, ws);
    hipLaunchKernelGGL(finalize, dim3(1), dim3(64), 0, stream, ws, out);
}